// Round 2
// baseline (2536.160 us; speedup 1.0000x reference)
//
#include <hip/hip_runtime.h>
#include <hip/hip_bf16.h>
#include <stdint.h>

#define NN  100000
#define NME 400000
#define NWE 200000
// D = 128, 3D = 384

typedef __bf16 bf16;
typedef __bf16 bf16x8 __attribute__((ext_vector_type(8)));
typedef float  f32x4  __attribute__((ext_vector_type(4)));

static __device__ __forceinline__ bf16 f2bf(float f) {
    union { unsigned int i; float f; } v; v.f = f;
    unsigned int r = (v.i + 0x7fffu + ((v.i >> 16) & 1u)) >> 16;
    union { unsigned short s; bf16 b; } u; u.s = (unsigned short)r;
    return u.b;
}

// ---------------------------------------------------------------------------
// Weight prep: read fp32 W1 (384x128), W2, W3 (128x128); write transposed bf16
// so the MFMA B-fragment (8 consecutive k for fixed n) is a contiguous 16B load.
// ---------------------------------------------------------------------------
__global__ void prep_weights(const float* __restrict__ W1, const float* __restrict__ W2,
                             const float* __restrict__ W3, bf16* __restrict__ W1t,
                             bf16* __restrict__ W2t, bf16* __restrict__ W3t) {
    int tid = blockIdx.x * 256 + threadIdx.x;
    if (tid < 49152) {                    // W1: k in [0,384), n in [0,128)
        int k = tid >> 7, n = tid & 127;
        W1t[n * 384 + k] = f2bf(W1[tid]);
    } else if (tid < 65536) {
        int t2 = tid - 49152;
        int k = t2 >> 7, n = t2 & 127;
        W2t[n * 128 + k] = f2bf(W2[t2]);
    } else if (tid < 81920) {
        int t2 = tid - 65536;
        int k = t2 >> 7, n = t2 & 127;
        W3t[n * 128 + k] = f2bf(W3[t2]);
    }
}

// ---------------------------------------------------------------------------
// Scatter-add: 16 threads per edge; each loads 8 consecutive fp32 (two f32x4,
// 32B coalesced) and does 8 fp32 atomicAdds into the receiver row.
// ---------------------------------------------------------------------------
__global__ __launch_bounds__(256) void scatter_add(const float* __restrict__ attr,
                                                   const int* __restrict__ recv,
                                                   float* __restrict__ agg, int nE) {
    int tid = blockIdx.x * 256 + threadIdx.x;
    int e = tid >> 4;
    int g = tid & 15;
    if (e >= nE) return;
    int r = recv[e];
    const float* src = attr + (size_t)e * 128 + g * 8;
    f32x4 lo = *(const f32x4*)(src);
    f32x4 hi = *(const f32x4*)(src + 4);
    float* dst = agg + (size_t)r * 128 + g * 8;
#pragma unroll
    for (int i = 0; i < 4; ++i) atomicAdd(dst + i, lo[i]);
#pragma unroll
    for (int i = 0; i < 4; ++i) atomicAdd(dst + 4 + i, hi[i]);
}

// ---------------------------------------------------------------------------
// Fused node MLP + LayerNorm.
// Block = 256 threads = 4 waves; each wave owns a 16-node strip (M=16, N=128).
// Layer1: K=384 over [x | mesh_agg | world_agg] (fp32 loads -> bf16 A-frags);
// Layers 2/3: K=128 with LDS round-trip (C-layout -> A-layout).
// LayerNorm via 16-lane xor-shuffles. fp32 output.
// ---------------------------------------------------------------------------
__global__ __launch_bounds__(256) void node_mlp(
    const float* __restrict__ x, const float* __restrict__ magg,
    const float* __restrict__ wagg, const bf16* __restrict__ W1t,
    const bf16* __restrict__ W2t, const bf16* __restrict__ W3t,
    const float* __restrict__ b1, const float* __restrict__ b2,
    const float* __restrict__ b3, const float* __restrict__ gam,
    const float* __restrict__ bet, float* __restrict__ out) {
    __shared__ bf16 sh[4 * 16 * 136];  // per-wave 16x(128+8) bf16; row stride 272B = 17*16B
    const int wave = threadIdx.x >> 6;
    const int lane = threadIdx.x & 63;
    const int quad = lane >> 4;
    const int l16 = lane & 15;
    const int node_base = blockIdx.x * 64 + wave * 16;
    bf16* shw = sh + wave * (16 * 136);

    int arow = node_base + l16;
    if (arow >= NN) arow = NN - 1;  // clamp; stores are guarded

    // ---- Layer 1: [16 x 384] @ [384 x 128] ----
    f32x4 acc[8];
#pragma unroll
    for (int t = 0; t < 8; ++t) acc[t] = (f32x4)0.0f;

#pragma unroll
    for (int ks = 0; ks < 12; ++ks) {
        int kg = ks * 32 + quad * 8;  // this lane's k-base in [0,384)
        const float* src;
        if (kg < 128)       src = x    + (size_t)arow * 128 + kg;
        else if (kg < 256)  src = magg + (size_t)arow * 128 + (kg - 128);
        else                src = wagg + (size_t)arow * 128 + (kg - 256);
        f32x4 lo = *(const f32x4*)(src);
        f32x4 hi = *(const f32x4*)(src + 4);
        bf16x8 afrag;
#pragma unroll
        for (int i = 0; i < 4; ++i) {
            afrag[i]     = f2bf(lo[i]);
            afrag[4 + i] = f2bf(hi[i]);
        }
#pragma unroll
        for (int t = 0; t < 8; ++t) {
            bf16x8 bfrag = *(const bf16x8*)(W1t + (t * 16 + l16) * 384 + ks * 32 + quad * 8);
            acc[t] = __builtin_amdgcn_mfma_f32_16x16x32_bf16(afrag, bfrag, acc[t], 0, 0, 0);
        }
    }
    // bias + relu, C-layout -> LDS (bf16)
#pragma unroll
    for (int t = 0; t < 8; ++t) {
        float bv = b1[t * 16 + l16];
#pragma unroll
        for (int r = 0; r < 4; ++r) {
            float h = acc[t][r] + bv;
            h = h > 0.0f ? h : 0.0f;
            shw[(quad * 4 + r) * 136 + t * 16 + l16] = f2bf(h);
        }
    }
    __syncthreads();

    // ---- Layer 2: [16 x 128] @ [128 x 128] ----
    bf16x8 a2[4];
#pragma unroll
    for (int ks = 0; ks < 4; ++ks)
        a2[ks] = *(const bf16x8*)(shw + l16 * 136 + ks * 32 + quad * 8);
#pragma unroll
    for (int t = 0; t < 8; ++t) acc[t] = (f32x4)0.0f;
#pragma unroll
    for (int ks = 0; ks < 4; ++ks) {
#pragma unroll
        for (int t = 0; t < 8; ++t) {
            bf16x8 bfrag = *(const bf16x8*)(W2t + (t * 16 + l16) * 128 + ks * 32 + quad * 8);
            acc[t] = __builtin_amdgcn_mfma_f32_16x16x32_bf16(a2[ks], bfrag, acc[t], 0, 0, 0);
        }
    }
    __syncthreads();
#pragma unroll
    for (int t = 0; t < 8; ++t) {
        float bv = b2[t * 16 + l16];
#pragma unroll
        for (int r = 0; r < 4; ++r) {
            float h = acc[t][r] + bv;
            h = h > 0.0f ? h : 0.0f;
            shw[(quad * 4 + r) * 136 + t * 16 + l16] = f2bf(h);
        }
    }
    __syncthreads();

    // ---- Layer 3: [16 x 128] @ [128 x 128] (no relu) ----
#pragma unroll
    for (int ks = 0; ks < 4; ++ks)
        a2[ks] = *(const bf16x8*)(shw + l16 * 136 + ks * 32 + quad * 8);
#pragma unroll
    for (int t = 0; t < 8; ++t) acc[t] = (f32x4)0.0f;
#pragma unroll
    for (int ks = 0; ks < 4; ++ks) {
#pragma unroll
        for (int t = 0; t < 8; ++t) {
            bf16x8 bfrag = *(const bf16x8*)(W3t + (t * 16 + l16) * 128 + ks * 32 + quad * 8);
            acc[t] = __builtin_amdgcn_mfma_f32_16x16x32_bf16(a2[ks], bfrag, acc[t], 0, 0, 0);
        }
    }
    // add b3
#pragma unroll
    for (int t = 0; t < 8; ++t) {
        float bv = b3[t * 16 + l16];
#pragma unroll
        for (int r = 0; r < 4; ++r) acc[t][r] += bv;
    }

    // ---- LayerNorm over the 128 cols of each row ----
    // Lane holds cols t*16+l16 of row quad*4+r; 16 lanes of a quad hold a
    // full row -> xor-shuffle reduce over masks 1,2,4,8.
    float gv[8], bv2[8];
#pragma unroll
    for (int t = 0; t < 8; ++t) {
        gv[t]  = gam[t * 16 + l16];
        bv2[t] = bet[t * 16 + l16];
    }
    float mean[4], rstd[4];
#pragma unroll
    for (int r = 0; r < 4; ++r) {
        float s = 0.0f, s2 = 0.0f;
#pragma unroll
        for (int t = 0; t < 8; ++t) {
            float v = acc[t][r];
            s += v;
            s2 += v * v;
        }
#pragma unroll
        for (int m = 1; m < 16; m <<= 1) {
            s  += __shfl_xor(s, m, 64);
            s2 += __shfl_xor(s2, m, 64);
        }
        float mu = s * (1.0f / 128.0f);
        float var = s2 * (1.0f / 128.0f) - mu * mu;
        mean[r] = mu;
        rstd[r] = rsqrtf(var + 1e-5f);
    }
#pragma unroll
    for (int r = 0; r < 4; ++r) {
        int row = node_base + quad * 4 + r;
        if (row < NN) {
#pragma unroll
            for (int t = 0; t < 8; ++t) {
                float o = (acc[t][r] - mean[r]) * rstd[r] * gv[t] + bv2[t];
                out[(size_t)row * 128 + t * 16 + l16] = o;
            }
        }
    }
}

// ---------------------------------------------------------------------------
extern "C" void kernel_launch(void* const* d_in, const int* in_sizes, int n_in,
                              void* d_out, int out_size, void* d_ws, size_t ws_size,
                              hipStream_t stream) {
    const float* x   = (const float*)d_in[0];
    const float* ea  = (const float*)d_in[1];
    const int*   ei  = (const int*)d_in[2];   // (2, NME) flat; recv row at offset NME
    const float* wea = (const float*)d_in[3];
    const int*   wei = (const int*)d_in[4];   // (2, NWE) flat; recv row at offset NWE
    const float* W1  = (const float*)d_in[5];
    const float* b1  = (const float*)d_in[6];
    const float* W2  = (const float*)d_in[7];
    const float* b2  = (const float*)d_in[8];
    const float* W3  = (const float*)d_in[9];
    const float* b3  = (const float*)d_in[10];
    const float* gam = (const float*)d_in[11];
    const float* bet = (const float*)d_in[12];

    char* ws = (char*)d_ws;
    float* magg = (float*)ws;                          // 100000*128*4 = 51,200,000 B
    float* wagg = (float*)(ws + 51200000);             // 51,200,000 B
    bf16* W1t = (bf16*)(ws + 102400000);               // 98,304 B
    bf16* W2t = (bf16*)(ws + 102400000 + 98304);       // 32,768 B
    bf16* W3t = (bf16*)(ws + 102400000 + 98304 + 32768);

    // zero the two fp32 aggregation buffers (ws is poisoned 0xAA each call)
    hipMemsetAsync(d_ws, 0, 102400000, stream);

    prep_weights<<<320, 256, 0, stream>>>(W1, W2, W3, W1t, W2t, W3t);

    scatter_add<<<(NME * 16) / 256, 256, 0, stream>>>(ea, ei + NME, magg, NME);
    scatter_add<<<(NWE * 16) / 256, 256, 0, stream>>>(wea, wei + NWE, wagg, NWE);

    node_mlp<<<(NN + 63) / 64, 256, 0, stream>>>(x, magg, wagg, W1t, W2t, W3t,
                                                 b1, b2, b3, gam, bet, (float*)d_out);
}

// Round 3
// 841.613 us; speedup vs baseline: 3.0135x; 3.0135x over previous
//
#include <hip/hip_runtime.h>
#include <hip/hip_bf16.h>
#include <stdint.h>

#define NN  100000
#define NME 400000
#define NWE 200000
// D = 128, 3D = 384

typedef __bf16 bf16;
typedef __bf16 bf16x8 __attribute__((ext_vector_type(8)));
typedef float  f32x4  __attribute__((ext_vector_type(4)));

static __device__ __forceinline__ bf16 f2bf(float f) {
    union { unsigned int i; float f; } v; v.f = f;
    unsigned int r = (v.i + 0x7fffu + ((v.i >> 16) & 1u)) >> 16;
    union { unsigned short s; bf16 b; } u; u.s = (unsigned short)r;
    return u.b;
}

// ---------------------------------------------------------------------------
// Weight prep: read fp32 W1 (384x128), W2, W3 (128x128); write transposed bf16
// so the MFMA B-fragment (8 consecutive k for fixed n) is a contiguous 16B load.
// ---------------------------------------------------------------------------
__global__ void prep_weights(const float* __restrict__ W1, const float* __restrict__ W2,
                             const float* __restrict__ W3, bf16* __restrict__ W1t,
                             bf16* __restrict__ W2t, bf16* __restrict__ W3t) {
    int tid = blockIdx.x * 256 + threadIdx.x;
    if (tid < 49152) {                    // W1: k in [0,384), n in [0,128)
        int k = tid >> 7, n = tid & 127;
        W1t[n * 384 + k] = f2bf(W1[tid]);
    } else if (tid < 65536) {
        int t2 = tid - 49152;
        int k = t2 >> 7, n = t2 & 127;
        W2t[n * 128 + k] = f2bf(W2[t2]);
    } else if (tid < 81920) {
        int t2 = tid - 65536;
        int k = t2 >> 7, n = t2 & 127;
        W3t[n * 128 + k] = f2bf(W3[t2]);
    }
}

// ---------------------------------------------------------------------------
// CSR build, step 1: per-receiver degree histogram (int atomics, tiny traffic).
// ---------------------------------------------------------------------------
__global__ __launch_bounds__(256) void count_edges(const int* __restrict__ mrecv,
                                                   const int* __restrict__ wrecv,
                                                   int* __restrict__ mdeg,
                                                   int* __restrict__ wdeg) {
    int t = blockIdx.x * 256 + threadIdx.x;
    if (t < NME) {
        atomicAdd(mdeg + mrecv[t], 1);
    } else {
        int t2 = t - NME;
        if (t2 < NWE) atomicAdd(wdeg + wrecv[t2], 1);
    }
}

// ---------------------------------------------------------------------------
// CSR build, step 2: exclusive prefix scan of degrees, in place (deg -> off),
// and copy into cursor array. Block 0 handles mesh, block 1 world.
// off[NN] is implied (= total edge count, a compile-time constant).
// ---------------------------------------------------------------------------
__global__ __launch_bounds__(1024) void scan_deg(int* __restrict__ mdeg, int* __restrict__ wdeg,
                                                 int* __restrict__ mcur, int* __restrict__ wcur) {
    __shared__ int s[1024];
    int* deg = (blockIdx.x == 0) ? mdeg : wdeg;
    int* cur = (blockIdx.x == 0) ? mcur : wcur;
    const int t = threadIdx.x;
    const int chunk = 98;  // 98*1024 >= 100000
    int lo = t * chunk;
    int hi = lo + chunk; if (hi > NN) hi = NN;
    int sum = 0;
    for (int i = lo; i < hi; ++i) sum += deg[i];
    s[t] = sum;
    __syncthreads();
    for (int d = 1; d < 1024; d <<= 1) {
        int v = (t >= d) ? s[t - d] : 0;
        __syncthreads();
        s[t] += v;
        __syncthreads();
    }
    int run = s[t] - sum;  // exclusive prefix for this thread's chunk
    for (int i = lo; i < hi; ++i) {
        int v = deg[i];
        deg[i] = run;
        cur[i] = run;
        run += v;
    }
}

// ---------------------------------------------------------------------------
// CSR build, step 3: bucket edge ids by receiver (cursor atomics).
// ---------------------------------------------------------------------------
__global__ __launch_bounds__(256) void fill_lists(const int* __restrict__ mrecv,
                                                  const int* __restrict__ wrecv,
                                                  int* __restrict__ mcur, int* __restrict__ wcur,
                                                  int* __restrict__ mlist, int* __restrict__ wlist) {
    int t = blockIdx.x * 256 + threadIdx.x;
    if (t < NME) {
        int r = mrecv[t];
        int p = atomicAdd(mcur + r, 1);
        mlist[p] = t;
    } else {
        int t2 = t - NME;
        if (t2 < NWE) {
            int r = wrecv[t2];
            int p = atomicAdd(wcur + r, 1);
            wlist[p] = t2;
        }
    }
}

// ---------------------------------------------------------------------------
// Gather: quarter-wave (16 lanes) per node; lane g sums floats [g*8, g*8+8)
// across the node's incoming edges (fp32 accum), writes bf16 agg row once.
// No float atomics, no RMW write amplification.
// ---------------------------------------------------------------------------
__global__ __launch_bounds__(256) void gather_sum(const float* __restrict__ attr,
                                                  const int* __restrict__ off,
                                                  const int* __restrict__ list,
                                                  bf16* __restrict__ agg, int nE) {
    int t = blockIdx.x * 256 + threadIdx.x;
    int node = t >> 4;
    int g = t & 15;
    if (node >= NN) return;
    int j0 = off[node];
    int j1 = (node == NN - 1) ? nE : off[node + 1];
    f32x4 lo = (f32x4)0.0f, hi = (f32x4)0.0f;
    for (int j = j0; j < j1; ++j) {
        int e = list[j];
        const float* src = attr + (size_t)e * 128 + g * 8;
        f32x4 a = *(const f32x4*)(src);
        f32x4 b = *(const f32x4*)(src + 4);
        lo += a;
        hi += b;
    }
    bf16x8 o;
#pragma unroll
    for (int i = 0; i < 4; ++i) {
        o[i]     = f2bf(lo[i]);
        o[4 + i] = f2bf(hi[i]);
    }
    *(bf16x8*)(agg + (size_t)node * 128 + g * 8) = o;
}

// ---------------------------------------------------------------------------
// Fused node MLP + LayerNorm.
// Block = 256 threads = 4 waves; each wave owns a 16-node strip (M=16, N=128).
// Layer1: K=384 over [x (fp32->bf16) | mesh_agg (bf16) | world_agg (bf16)];
// Layers 2/3: K=128 with LDS round-trip (C-layout -> A-layout).
// LayerNorm via 16-lane xor-shuffles. fp32 output.
// ---------------------------------------------------------------------------
__global__ __launch_bounds__(256) void node_mlp(
    const float* __restrict__ x, const bf16* __restrict__ magg,
    const bf16* __restrict__ wagg, const bf16* __restrict__ W1t,
    const bf16* __restrict__ W2t, const bf16* __restrict__ W3t,
    const float* __restrict__ b1, const float* __restrict__ b2,
    const float* __restrict__ b3, const float* __restrict__ gam,
    const float* __restrict__ bet, float* __restrict__ out) {
    __shared__ bf16 sh[4 * 16 * 136];  // per-wave 16x(128+8) bf16; row stride 272B = 17*16B
    const int wave = threadIdx.x >> 6;
    const int lane = threadIdx.x & 63;
    const int quad = lane >> 4;
    const int l16 = lane & 15;
    const int node_base = blockIdx.x * 64 + wave * 16;
    bf16* shw = sh + wave * (16 * 136);

    int arow = node_base + l16;
    if (arow >= NN) arow = NN - 1;  // clamp; stores are guarded

    // ---- Layer 1: [16 x 384] @ [384 x 128] ----
    f32x4 acc[8];
#pragma unroll
    for (int t = 0; t < 8; ++t) acc[t] = (f32x4)0.0f;

#pragma unroll
    for (int ks = 0; ks < 12; ++ks) {
        int kg = ks * 32 + quad * 8;  // this lane's k-base in [0,384)
        bf16x8 afrag;
        if (kg < 128) {
            const float* src = x + (size_t)arow * 128 + kg;
            f32x4 lo = *(const f32x4*)(src);
            f32x4 hi = *(const f32x4*)(src + 4);
#pragma unroll
            for (int i = 0; i < 4; ++i) {
                afrag[i]     = f2bf(lo[i]);
                afrag[4 + i] = f2bf(hi[i]);
            }
        } else if (kg < 256) {
            afrag = *(const bf16x8*)(magg + (size_t)arow * 128 + (kg - 128));
        } else {
            afrag = *(const bf16x8*)(wagg + (size_t)arow * 128 + (kg - 256));
        }
#pragma unroll
        for (int t = 0; t < 8; ++t) {
            bf16x8 bfrag = *(const bf16x8*)(W1t + (t * 16 + l16) * 384 + ks * 32 + quad * 8);
            acc[t] = __builtin_amdgcn_mfma_f32_16x16x32_bf16(afrag, bfrag, acc[t], 0, 0, 0);
        }
    }
    // bias + relu, C-layout -> LDS (bf16)
#pragma unroll
    for (int t = 0; t < 8; ++t) {
        float bv = b1[t * 16 + l16];
#pragma unroll
        for (int r = 0; r < 4; ++r) {
            float h = acc[t][r] + bv;
            h = h > 0.0f ? h : 0.0f;
            shw[(quad * 4 + r) * 136 + t * 16 + l16] = f2bf(h);
        }
    }
    __syncthreads();

    // ---- Layer 2: [16 x 128] @ [128 x 128] ----
    bf16x8 a2[4];
#pragma unroll
    for (int ks = 0; ks < 4; ++ks)
        a2[ks] = *(const bf16x8*)(shw + l16 * 136 + ks * 32 + quad * 8);
#pragma unroll
    for (int t = 0; t < 8; ++t) acc[t] = (f32x4)0.0f;
#pragma unroll
    for (int ks = 0; ks < 4; ++ks) {
#pragma unroll
        for (int t = 0; t < 8; ++t) {
            bf16x8 bfrag = *(const bf16x8*)(W2t + (t * 16 + l16) * 128 + ks * 32 + quad * 8);
            acc[t] = __builtin_amdgcn_mfma_f32_16x16x32_bf16(a2[ks], bfrag, acc[t], 0, 0, 0);
        }
    }
    __syncthreads();
#pragma unroll
    for (int t = 0; t < 8; ++t) {
        float bv = b2[t * 16 + l16];
#pragma unroll
        for (int r = 0; r < 4; ++r) {
            float h = acc[t][r] + bv;
            h = h > 0.0f ? h : 0.0f;
            shw[(quad * 4 + r) * 136 + t * 16 + l16] = f2bf(h);
        }
    }
    __syncthreads();

    // ---- Layer 3: [16 x 128] @ [128 x 128] (no relu) ----
#pragma unroll
    for (int ks = 0; ks < 4; ++ks)
        a2[ks] = *(const bf16x8*)(shw + l16 * 136 + ks * 32 + quad * 8);
#pragma unroll
    for (int t = 0; t < 8; ++t) acc[t] = (f32x4)0.0f;
#pragma unroll
    for (int ks = 0; ks < 4; ++ks) {
#pragma unroll
        for (int t = 0; t < 8; ++t) {
            bf16x8 bfrag = *(const bf16x8*)(W3t + (t * 16 + l16) * 128 + ks * 32 + quad * 8);
            acc[t] = __builtin_amdgcn_mfma_f32_16x16x32_bf16(a2[ks], bfrag, acc[t], 0, 0, 0);
        }
    }
    // add b3
#pragma unroll
    for (int t = 0; t < 8; ++t) {
        float bv = b3[t * 16 + l16];
#pragma unroll
        for (int r = 0; r < 4; ++r) acc[t][r] += bv;
    }

    // ---- LayerNorm over the 128 cols of each row ----
    float gv[8], bv2[8];
#pragma unroll
    for (int t = 0; t < 8; ++t) {
        gv[t]  = gam[t * 16 + l16];
        bv2[t] = bet[t * 16 + l16];
    }
    float mean[4], rstd[4];
#pragma unroll
    for (int r = 0; r < 4; ++r) {
        float s = 0.0f, s2 = 0.0f;
#pragma unroll
        for (int t = 0; t < 8; ++t) {
            float v = acc[t][r];
            s += v;
            s2 += v * v;
        }
#pragma unroll
        for (int m = 1; m < 16; m <<= 1) {
            s  += __shfl_xor(s, m, 64);
            s2 += __shfl_xor(s2, m, 64);
        }
        float mu = s * (1.0f / 128.0f);
        float var = s2 * (1.0f / 128.0f) - mu * mu;
        mean[r] = mu;
        rstd[r] = rsqrtf(var + 1e-5f);
    }
#pragma unroll
    for (int r = 0; r < 4; ++r) {
        int row = node_base + quad * 4 + r;
        if (row < NN) {
#pragma unroll
            for (int t = 0; t < 8; ++t) {
                float o = (acc[t][r] - mean[r]) * rstd[r] * gv[t] + bv2[t];
                out[(size_t)row * 128 + t * 16 + l16] = o;
            }
        }
    }
}

// ---------------------------------------------------------------------------
extern "C" void kernel_launch(void* const* d_in, const int* in_sizes, int n_in,
                              void* d_out, int out_size, void* d_ws, size_t ws_size,
                              hipStream_t stream) {
    const float* x   = (const float*)d_in[0];
    const float* ea  = (const float*)d_in[1];
    const int*   ei  = (const int*)d_in[2];   // (2, NME) flat; recv row at offset NME
    const float* wea = (const float*)d_in[3];
    const int*   wei = (const int*)d_in[4];   // (2, NWE) flat; recv row at offset NWE
    const float* W1  = (const float*)d_in[5];
    const float* b1  = (const float*)d_in[6];
    const float* W2  = (const float*)d_in[7];
    const float* b2  = (const float*)d_in[8];
    const float* W3  = (const float*)d_in[9];
    const float* b3  = (const float*)d_in[10];
    const float* gam = (const float*)d_in[11];
    const float* bet = (const float*)d_in[12];

    char* ws = (char*)d_ws;
    bf16* magg = (bf16*)(ws);                      // 25,600,000 B
    bf16* wagg = (bf16*)(ws + 25600000);           // 25,600,000 B
    bf16* W1t  = (bf16*)(ws + 51200000);           // 98,304 B
    bf16* W2t  = (bf16*)(ws + 51298304);           // 32,768 B
    bf16* W3t  = (bf16*)(ws + 51331072);           // 32,768 B
    int*  mdeg = (int*)(ws + 51363840);            // 400,000 B (deg -> off in place)
    int*  wdeg = (int*)(ws + 51763840);            // 400,000 B (contiguous with mdeg)
    int*  mcur = (int*)(ws + 52163840);            // 400,000 B
    int*  wcur = (int*)(ws + 52563840);            // 400,000 B
    int*  mlist = (int*)(ws + 52963840);           // 1,600,000 B
    int*  wlist = (int*)(ws + 54563840);           // 800,000 B   (total 55,363,840)

    // zero only the two degree arrays (contiguous 800 KB)
    hipMemsetAsync(ws + 51363840, 0, 800000, stream);

    prep_weights<<<320, 256, 0, stream>>>(W1, W2, W3, W1t, W2t, W3t);

    count_edges<<<(NME + NWE + 255) / 256, 256, 0, stream>>>(ei + NME, wei + NWE, mdeg, wdeg);
    scan_deg<<<2, 1024, 0, stream>>>(mdeg, wdeg, mcur, wcur);
    fill_lists<<<(NME + NWE + 255) / 256, 256, 0, stream>>>(ei + NME, wei + NWE,
                                                            mcur, wcur, mlist, wlist);

    gather_sum<<<(NN * 16 + 255) / 256, 256, 0, stream>>>(ea, mdeg, mlist, magg, NME);
    gather_sum<<<(NN * 16 + 255) / 256, 256, 0, stream>>>(wea, wdeg, wlist, wagg, NWE);

    node_mlp<<<(NN + 63) / 64, 256, 0, stream>>>(x, magg, wagg, W1t, W2t, W3t,
                                                 b1, b2, b3, gam, bet, (float*)d_out);
}